// Round 7
// baseline (362.784 us; speedup 1.0000x reference)
//
#include <hip/hip_runtime.h>

typedef unsigned short u16;
typedef unsigned int   u32;
typedef unsigned long long u64;
typedef __bf16 bf16x8 __attribute__((ext_vector_type(8)));
typedef float  f32x16 __attribute__((ext_vector_type(16)));

#define AS1 __attribute__((address_space(1)))
#define AS3 __attribute__((address_space(3)))

#define M_TOK 8192
#define K_DIM 4096
#define N_DIM 4096
#define BK    32
#define NKT   (K_DIM / BK)   // 128

static __device__ __forceinline__ u16 f2bf(float f) {
  u32 u = __builtin_bit_cast(u32, f);
  return (u16)((u + (0x7FFFu + ((u >> 16) & 1u))) >> 16);
}

// global -> LDS direct copy, 16B per lane. LDS dest is wave-uniform base;
// HW stores lane l at dest + l*16 (linear, rule #21).
static __device__ __forceinline__ void gld_lds16(const void* g, void* l) {
  __builtin_amdgcn_global_load_lds((AS1 u32*)(u64)g, (AS3 u32*)(u32)(u64)l, 16, 0, 0);
}

// ---- fused prep: blocks [0, M_TOK) do per-token x->bf16 + LoRA mid;
//      blocks [M_TOK, M_TOK+2048) convert W_main f32->bf16 (grid-stride). ----
__global__ __launch_bounds__(256) void k_prep(const float* __restrict__ x,
                                              const float* __restrict__ WA,
                                              const float* __restrict__ W,
                                              u16* __restrict__ xb,
                                              float* __restrict__ mid,
                                              u16* __restrict__ Wb) {
  const int t = threadIdx.x;
  if (blockIdx.x >= M_TOK) {
    const int cb = blockIdx.x - M_TOK;           // 0..2047
    const float4* W4 = (const float4*)W;
    ushort4* Wb4 = (ushort4*)Wb;
    const int n4 = (N_DIM * K_DIM) / 4;
    int i = cb * 256 + t;
    for (; i < n4; i += 2048 * 256) {
      float4 v = W4[i];
      ushort4 o;
      o.x = f2bf(v.x); o.y = f2bf(v.y); o.z = f2bf(v.z); o.w = f2bf(v.w);
      Wb4[i] = o;
    }
    return;
  }
  const int m = blockIdx.x;
  const float4* xr = (const float4*)(x + (size_t)m * K_DIM);
  ushort4* xbr = (ushort4*)(xb + (size_t)m * K_DIM);
  float a[8] = {0.f,0.f,0.f,0.f,0.f,0.f,0.f,0.f};
  #pragma unroll
  for (int i = 0; i < 4; ++i) {
    const int k4 = t + i * 256;
    float4 v = xr[k4];
    ushort4 o;
    o.x = f2bf(v.x); o.y = f2bf(v.y); o.z = f2bf(v.z); o.w = f2bf(v.w);
    xbr[k4] = o;
    #pragma unroll
    for (int r = 0; r < 8; ++r) {
      float4 wv = ((const float4*)(WA + (size_t)r * K_DIM))[k4];
      a[r] += v.x * wv.x + v.y * wv.y + v.z * wv.z + v.w * wv.w;
    }
  }
  #pragma unroll
  for (int r = 0; r < 8; ++r) {
    #pragma unroll
    for (int off = 32; off > 0; off >>= 1)
      a[r] += __shfl_down(a[r], off);
  }
  __shared__ float red[4][8];
  const int w = t >> 6, l = t & 63;
  if (l == 0) {
    #pragma unroll
    for (int r = 0; r < 8; ++r) red[w][r] = a[r];
  }
  __syncthreads();
  if (t < 8)
    mid[(size_t)m * 8 + t] = 2.0f * (red[0][t] + red[1][t] + red[2][t] + red[3][t]);
}

// ---- main GEMM: 256x256 tile, BK=32, 8 waves (2Mx4N), 4-deep LDS ring,
// counted-vmcnt pipeline + setprio + XCD swizzle + LDS XOR swizzle
// (conflicts = 0) + literal-index unroll (R4) + single barrier/tile (R5).
// R7: 32x32x16 MFMA (2495 TF ceiling vs 2176 for 16x16x32; half the MFMA
// instruction count at identical LDS traffic and register footprint).
// R6's register double-buffer REVERTED (it spilled: +96 MiB scratch writes).
//
// Per wave (tile 128x64): A-frags 4m(32 rows) x 2ks, B-frags 2n x 2ks,
// 12 ds_read_b128 per K32 tile, 16 MFMA (4m x 2n x 2ks), acc[4][2] f32x16.
//
// Read swizzle: LDS[r][slot s] holds global chunk s ^ ((r>>1)&3) (staging
// pre-swizzle (t&3)^((t>>3)&3), rows = t>>2). Frag read of global chunk
// c = 2ks + hk (hk = lane>>5) at row r reads slot c ^ ((r>>1)&3); with
// (r>>1)&3 = ((lane&31)>>1)&3 this is wave-loop-invariant. Bank passes
// (16 lanes): 16 distinct rows, fixed chunk -> same conflict-free pattern
// R3 measured at 0.
//
// Ledger unchanged (FIFO, 4 gld_lds/tile/wave): stage kt+3 during kt into
// buf (kt+3)&3 (= buf of kt-1, reads done); end-of-kt vmcnt(8); tail 8->4->0.
__global__ __launch_bounds__(512, 2) void k_gemm(
    const u16* __restrict__ A, const u16* __restrict__ B,
    const float* __restrict__ bias, const int* __restrict__ mask,
    const float* __restrict__ mid, const float* __restrict__ WBw,
    float* __restrict__ out) {
  __shared__ u16 smem[4][2][256][BK];   // [buf][A=0/B=1][row][k] = 128 KiB

  const int t = threadIdx.x;
  const int wid = t >> 6, l = t & 63;
  const int wr = wid >> 2, wc = wid & 3;   // 2x4 wave grid -> 128x64 out/wave
  const int l31 = l & 31, hk = l >> 5;

  // T1: XCD-aware swizzle (512 blocks, 512%8==0 -> bijective)
  const int bid = blockIdx.x;
  const int swz = (bid & 7) * 64 + (bid >> 3);
  const int bm = swz >> 4, bn = swz & 15;

  const char* Ag = (const char*)(A + (size_t)bm * 256 * K_DIM);
  const char* Bg = (const char*)(B + (size_t)bn * 256 * K_DIM);
  const size_t rowb = (size_t)K_DIM * 2;

  // staging: q in {A-lo, A-hi, B-lo, B-hi}; 512 thr x 16B = 8KB per q.
  // thread t covers row t>>2; source 16B-chunk is the pre-swizzle
  // (t&3)^((t>>3)&3) (4-lane groups stay within one 64B row-segment).
  const int srow = t >> 2;
  const int schk = (((t & 3) ^ ((t >> 3) & 3)) * 16);
  const char* bA0 = Ag + (size_t)srow * rowb + schk;
  const char* bA1 = Ag + (size_t)(128 + srow) * rowb + schk;
  const char* bB0 = Bg + (size_t)srow * rowb + schk;
  const char* bB1 = Bg + (size_t)(128 + srow) * rowb + schk;
  char* lbase = (char*)&smem[0][0][0][0] + wid * 1024;

  f32x16 acc[4][2];
  #pragma unroll
  for (int m = 0; m < 4; ++m)
    #pragma unroll
    for (int n = 0; n < 2; ++n)
      acc[m][n] = (f32x16){0.f,0.f,0.f,0.f,0.f,0.f,0.f,0.f,
                           0.f,0.f,0.f,0.f,0.f,0.f,0.f,0.f};

  // prologue: tiles 0..2 into bufs 0..2
  #pragma unroll
  for (int pk = 0; pk < 3; ++pk) {
    gld_lds16(bA0 + pk * 64, lbase + pk * 32768);
    gld_lds16(bA1 + pk * 64, lbase + pk * 32768 + 8192);
    gld_lds16(bB0 + pk * 64, lbase + pk * 32768 + 16384);
    gld_lds16(bB1 + pk * 64, lbase + pk * 32768 + 24576);
  }
  asm volatile("s_waitcnt vmcnt(8)" ::: "memory");
  __builtin_amdgcn_s_barrier();

  // read-side swizzled column offsets (u16 units), wave-invariant:
  // chunk(ks) = (2*ks + hk) ^ ((l31>>1)&3), ks in {0,1}
  const int rsw = (l31 >> 1) & 3;
  const int cofs[2] = { ((0 + hk) ^ rsw) * 8, ((2 + hk) ^ rsw) * 8 };

  // running stage pointers, pre-offset to tile 3 (= kt+3 at ktb=0)
  const char* gA0 = bA0 + 192;
  const char* gA1 = bA1 + 192;
  const char* gB0 = bB0 + 192;
  const char* gB1 = bB1 + 192;

  // One K32-tile, single-barrier form, 32x32x16 MFMA.
  #define K_TILE(BUFC, NB, DOSTAGE, GOFF, WAIT) do {                         \
    const u16* Ab_ = &smem[BUFC][0][wr * 128 + l31][0];                      \
    const u16* Bb_ = &smem[BUFC][1][wc * 64 + l31][0];                       \
    bf16x8 af_[8], bf_[4];                                                   \
    _Pragma("unroll")                                                        \
    for (int m = 0; m < 4; ++m)                                              \
      _Pragma("unroll")                                                      \
      for (int ks = 0; ks < 2; ++ks)                                         \
        af_[m * 2 + ks] = *(const bf16x8*)(Ab_ + m * 32 * BK + cofs[ks]);    \
    _Pragma("unroll")                                                        \
    for (int n = 0; n < 2; ++n)                                              \
      _Pragma("unroll")                                                      \
      for (int ks = 0; ks < 2; ++ks)                                         \
        bf_[n * 2 + ks] = *(const bf16x8*)(Bb_ + n * 32 * BK + cofs[ks]);    \
    if (DOSTAGE) {                                                           \
      gld_lds16(gA0 + (GOFF), lbase + (NB) * 32768);                         \
      gld_lds16(gA1 + (GOFF), lbase + (NB) * 32768 + 8192);                  \
      gld_lds16(gB0 + (GOFF), lbase + (NB) * 32768 + 16384);                 \
      gld_lds16(gB1 + (GOFF), lbase + (NB) * 32768 + 24576);                 \
    }                                                                        \
    __builtin_amdgcn_s_setprio(1);                                           \
    _Pragma("unroll")                                                        \
    for (int m = 0; m < 4; ++m)                                              \
      _Pragma("unroll")                                                      \
      for (int n = 0; n < 2; ++n)                                            \
        _Pragma("unroll")                                                    \
        for (int ks = 0; ks < 2; ++ks)                                       \
          acc[m][n] = __builtin_amdgcn_mfma_f32_32x32x16_bf16(               \
              af_[m * 2 + ks], bf_[n * 2 + ks], acc[m][n], 0, 0, 0);         \
    __builtin_amdgcn_s_setprio(0);                                           \
    WAIT;                                                                    \
    __builtin_amdgcn_s_barrier();                                            \
  } while (0)

  #define VM8 asm volatile("s_waitcnt vmcnt(8)" ::: "memory")
  #define VM4 asm volatile("s_waitcnt vmcnt(4)" ::: "memory")
  #define VM0 asm volatile("s_waitcnt vmcnt(0)" ::: "memory")

  // steady: 31 groups of 4 tiles (kt = 0..123), all stage, all vmcnt(8)
  for (int ktb = 0; ktb < NKT - 4; ktb += 4) {
    K_TILE(0, 3, true, 0,   VM8);
    K_TILE(1, 0, true, 64,  VM8);
    K_TILE(2, 1, true, 128, VM8);
    K_TILE(3, 2, true, 192, VM8);
    gA0 += 256; gA1 += 256; gB0 += 256; gB1 += 256;
  }
  // peeled tail: kt = 124 (stage tile 127 at GOFF 0), 125, 126, 127
  K_TILE(0, 3, true,  0, VM8);
  K_TILE(1, 0, false, 0, VM4);
  K_TILE(2, 1, false, 0, VM0);
  K_TILE(3, 2, false, 0, ((void)0));

  #undef K_TILE
  #undef VM8
  #undef VM4
  #undef VM0

  // ---- epilogue: bias + masked rank-8 LoRA, fp32 out ----
  // 32x32 C/D layout: col = gn0 + n*32 + (l&31),
  //                   row = gm0 + m*32 + (j&3) + 8*(j>>2) + 4*hk.
  const int gn0 = bn * 256 + wc * 64;
  const size_t gm0 = (size_t)bm * 256 + wr * 128;
  float wbv[2][8]; float bv[2];
  #pragma unroll
  for (int n = 0; n < 2; ++n) {
    const int gn = gn0 + n * 32 + l31;
    bv[n] = bias[gn];
    const float4 w0 = ((const float4*)(WBw + (size_t)gn * 8))[0];
    const float4 w1 = ((const float4*)(WBw + (size_t)gn * 8))[1];
    wbv[n][0] = w0.x; wbv[n][1] = w0.y; wbv[n][2] = w0.z; wbv[n][3] = w0.w;
    wbv[n][4] = w1.x; wbv[n][5] = w1.y; wbv[n][6] = w1.z; wbv[n][7] = w1.w;
  }
  #pragma unroll
  for (int m = 0; m < 4; ++m) {
    #pragma unroll
    for (int j = 0; j < 16; ++j) {
      const size_t gm = gm0 + m * 32 + (j & 3) + 8 * (j >> 2) + 4 * hk;
      const int msk = mask[gm];
      const float4 m0 = ((const float4*)(mid + gm * 8))[0];
      const float4 m1 = ((const float4*)(mid + gm * 8))[1];
      float* orow = out + gm * (size_t)N_DIM;
      #pragma unroll
      for (int n = 0; n < 2; ++n) {
        const float lora =
            m0.x * wbv[n][0] + m0.y * wbv[n][1] + m0.z * wbv[n][2] + m0.w * wbv[n][3] +
            m1.x * wbv[n][4] + m1.y * wbv[n][5] + m1.z * wbv[n][6] + m1.w * wbv[n][7];
        orow[gn0 + n * 32 + l31] = acc[m][n][j] + bv[n] + (msk ? lora : 0.0f);
      }
    }
  }
}

extern "C" void kernel_launch(void* const* d_in, const int* in_sizes, int n_in,
                              void* d_out, int out_size, void* d_ws, size_t ws_size,
                              hipStream_t stream) {
  (void)in_sizes; (void)n_in; (void)out_size; (void)ws_size;
  const float* x     = (const float*)d_in[0];
  const int*   mask  = (const int*)d_in[1];
  const float* Wm    = (const float*)d_in[2];
  const float* bmain = (const float*)d_in[3];
  const float* WA    = (const float*)d_in[4];
  const float* WB    = (const float*)d_in[5];
  float* out = (float*)d_out;

  u16* xb  = (u16*)d_ws;                                // 64 MiB
  u16* wb  = xb + (size_t)M_TOK * K_DIM;                // 32 MiB
  float* mid = (float*)(wb + (size_t)N_DIM * K_DIM);    // 256 KiB

  k_prep<<<M_TOK + 2048, 256, 0, stream>>>(x, WA, Wm, xb, mid, wb);
  dim3 grid((M_TOK / 256) * (N_DIM / 256));             // 512 blocks
  k_gemm<<<grid, 512, 0, stream>>>(xb, wb, bmain, mask, mid, WB, out);
}

// Round 8
// 326.542 us; speedup vs baseline: 1.1110x; 1.1110x over previous
//
#include <hip/hip_runtime.h>

typedef unsigned short u16;
typedef unsigned int   u32;
typedef unsigned long long u64;
typedef __bf16 bf16x8 __attribute__((ext_vector_type(8)));
typedef float  f32x4  __attribute__((ext_vector_type(4)));

#define AS1 __attribute__((address_space(1)))
#define AS3 __attribute__((address_space(3)))

#define M_TOK 8192
#define K_DIM 4096
#define N_DIM 4096
#define BK    32
#define NKT   (K_DIM / BK)   // 128

static __device__ __forceinline__ u16 f2bf(float f) {
  u32 u = __builtin_bit_cast(u32, f);
  return (u16)((u + (0x7FFFu + ((u >> 16) & 1u))) >> 16);
}

// global -> LDS direct copy, 16B per lane. LDS dest is wave-uniform base;
// HW stores lane l at dest + l*16 (linear, rule #21).
static __device__ __forceinline__ void gld_lds16(const void* g, void* l) {
  __builtin_amdgcn_global_load_lds((AS1 u32*)(u64)g, (AS3 u32*)(u32)(u64)l, 16, 0, 0);
}

// ---- fused prep: blocks [0, M_TOK) do per-token x->bf16 + LoRA mid;
//      blocks [M_TOK, M_TOK+2048) convert W_main f32->bf16 (grid-stride). ----
__global__ __launch_bounds__(256) void k_prep(const float* __restrict__ x,
                                              const float* __restrict__ WA,
                                              const float* __restrict__ W,
                                              u16* __restrict__ xb,
                                              float* __restrict__ mid,
                                              u16* __restrict__ Wb) {
  const int t = threadIdx.x;
  if (blockIdx.x >= M_TOK) {
    const int cb = blockIdx.x - M_TOK;           // 0..2047
    const float4* W4 = (const float4*)W;
    ushort4* Wb4 = (ushort4*)Wb;
    const int n4 = (N_DIM * K_DIM) / 4;
    int i = cb * 256 + t;
    for (; i < n4; i += 2048 * 256) {
      float4 v = W4[i];
      ushort4 o;
      o.x = f2bf(v.x); o.y = f2bf(v.y); o.z = f2bf(v.z); o.w = f2bf(v.w);
      Wb4[i] = o;
    }
    return;
  }
  const int m = blockIdx.x;
  const float4* xr = (const float4*)(x + (size_t)m * K_DIM);
  ushort4* xbr = (ushort4*)(xb + (size_t)m * K_DIM);
  float a[8] = {0.f,0.f,0.f,0.f,0.f,0.f,0.f,0.f};
  #pragma unroll
  for (int i = 0; i < 4; ++i) {
    const int k4 = t + i * 256;
    float4 v = xr[k4];
    ushort4 o;
    o.x = f2bf(v.x); o.y = f2bf(v.y); o.z = f2bf(v.z); o.w = f2bf(v.w);
    xbr[k4] = o;
    #pragma unroll
    for (int r = 0; r < 8; ++r) {
      float4 wv = ((const float4*)(WA + (size_t)r * K_DIM))[k4];
      a[r] += v.x * wv.x + v.y * wv.y + v.z * wv.z + v.w * wv.w;
    }
  }
  #pragma unroll
  for (int r = 0; r < 8; ++r) {
    #pragma unroll
    for (int off = 32; off > 0; off >>= 1)
      a[r] += __shfl_down(a[r], off);
  }
  __shared__ float red[4][8];
  const int w = t >> 6, l = t & 63;
  if (l == 0) {
    #pragma unroll
    for (int r = 0; r < 8; ++r) red[w][r] = a[r];
  }
  __syncthreads();
  if (t < 8)
    mid[(size_t)m * 8 + t] = 2.0f * (red[0][t] + red[1][t] + red[2][t] + red[3][t]);
}

// ---- main GEMM: 256x256 tile, BK=32, 8 waves (2Mx4N), 4-deep LDS ring.
// R8: ROTATING READ-AHEAD at constant 12-b128 frag footprint.
//   R5 serialized: all 12 ds_reads at tile start -> 8-wave LDS jam (~1150cy)
//   then MFMA burst (1242cy) with LDS idle => tile 2550cy.  R6's full
//   double-buffer spilled (24 b128 live).  Here kt+1's reads are issued in
//   the register slots freed by kt's MFMA subclusters:
//     stage(kt+3) -> MFMA m0-3 -> load afL(kt+1) into af[0:4]
//                 -> MFMA m4-7 -> load afH(kt+1)+bf(kt+1)
//     -> vmcnt(4) -> barrier
//   Peak live frags = 12 b128 (as R5).  Only bf(kt+1) (32 reads/CU ~350cy)
//   remains at the boundary.
//
// Ledger (FIFO, 4 gld_lds/tile/wave), steady tile kt:
//   - at kt start: outstanding = s(kt+2) (4).  Issue s(kt+3) -> 8.
//   - end-of-kt vmcnt(4): retires s(kt+2); barrier makes it all-wave.
//   => at kt's start barrier, tiles kt AND kt+1 are fully resident, which
//      legalizes the mid-tile reads of kt+1.  (Prologue: stage 0,1,2,
//      vmcnt(4) retires s0,s1 -> both 0 and 1 resident at loop entry.)
//   - stage into buf[(kt+3)&3] = buf[kt-1]: kt-1's reads (issued during
//     kt-2) drained before MFMA(kt-1), two barriers ago -> safe.
//   Tail: VM4@124 (retire s126), VM0@125 (retire s127), none after;
//   read-ahead off at kt=127.
__global__ __launch_bounds__(512, 2) void k_gemm(
    const u16* __restrict__ A, const u16* __restrict__ B,
    const float* __restrict__ bias, const int* __restrict__ mask,
    const float* __restrict__ mid, const float* __restrict__ WBw,
    float* __restrict__ out) {
  __shared__ u16 smem[4][2][256][BK];   // [buf][A=0/B=1][row][k] = 128 KiB

  const int t = threadIdx.x;
  const int wid = t >> 6, l = t & 63;
  const int wr = wid >> 2, wc = wid & 3;   // 2x4 wave grid -> 128x64 out/wave
  const int fr = l & 15, fq = l >> 4;

  // T1: XCD-aware swizzle (512 blocks, 512%8==0 -> bijective)
  const int bid = blockIdx.x;
  const int swz = (bid & 7) * 64 + (bid >> 3);
  const int bm = swz >> 4, bn = swz & 15;

  const char* Ag = (const char*)(A + (size_t)bm * 256 * K_DIM);
  const char* Bg = (const char*)(B + (size_t)bn * 256 * K_DIM);
  const size_t rowb = (size_t)K_DIM * 2;

  // staging: q in {A-lo, A-hi, B-lo, B-hi}; 512 thr x 16B = 8KB per q.
  // thread t covers row t>>2; source 16B-chunk is the T2 pre-swizzle
  // (t&3)^((t>>3)&3) (4-lane groups stay within one 64B row-segment).
  const int srow = t >> 2;
  const int schk = (((t & 3) ^ ((t >> 3) & 3)) * 16);
  const char* bA0 = Ag + (size_t)srow * rowb + schk;
  const char* bA1 = Ag + (size_t)(128 + srow) * rowb + schk;
  const char* bB0 = Bg + (size_t)srow * rowb + schk;
  const char* bB1 = Bg + (size_t)(128 + srow) * rowb + schk;
  char* lbase = (char*)&smem[0][0][0][0] + wid * 1024;

  f32x4 acc[8][4];
  #pragma unroll
  for (int m = 0; m < 8; ++m)
    #pragma unroll
    for (int n = 0; n < 4; ++n)
      acc[m][n] = (f32x4){0.f, 0.f, 0.f, 0.f};

  // prologue: tiles 0..2 into bufs 0..2; retire s0 AND s1 before barrier
  #pragma unroll
  for (int pk = 0; pk < 3; ++pk) {
    gld_lds16(bA0 + pk * 64, lbase + pk * 32768);
    gld_lds16(bA1 + pk * 64, lbase + pk * 32768 + 8192);
    gld_lds16(bB0 + pk * 64, lbase + pk * 32768 + 16384);
    gld_lds16(bB1 + pk * 64, lbase + pk * 32768 + 24576);
  }
  asm volatile("s_waitcnt vmcnt(4)" ::: "memory");
  __builtin_amdgcn_s_barrier();

  // T2 read-side swizzled column (u16 units), wave-invariant
  const int csw = (fq ^ ((fr >> 1) & 3)) * 8;

  // running stage pointers, pre-offset to tile 3 (= kt+3 at ktb=0)
  const char* gA0 = bA0 + 192;
  const char* gA1 = bA1 + 192;
  const char* gB0 = bB0 + 192;
  const char* gB1 = bB1 + 192;

  // loop-carried fragment registers (12 x b128), static indexing only
  bf16x8 af[8], bf[4];

  // preload frags(0) from buf 0
  {
    const u16* Ap_ = &smem[0][0][wr * 128 + fr][csw];
    const u16* Bp_ = &smem[0][1][wc * 64 + fr][csw];
    #pragma unroll
    for (int m = 0; m < 8; ++m) af[m] = *(const bf16x8*)(Ap_ + m * 16 * BK);
    #pragma unroll
    for (int n = 0; n < 4; ++n) bf[n] = *(const bf16x8*)(Bp_ + n * 16 * BK);
  }

  // One K32-tile: RBUF = buf of kt+1 (read-ahead), SB = stage dest buf.
  #define K_TILE(RBUF, SB, DOSTAGE, DOREAD, GOFF, WAIT) do {                 \
    if (DOSTAGE) {                                                           \
      gld_lds16(gA0 + (GOFF), lbase + (SB) * 32768);                         \
      gld_lds16(gA1 + (GOFF), lbase + (SB) * 32768 + 8192);                  \
      gld_lds16(gB0 + (GOFF), lbase + (SB) * 32768 + 16384);                 \
      gld_lds16(gB1 + (GOFF), lbase + (SB) * 32768 + 24576);                 \
    }                                                                        \
    __builtin_amdgcn_s_setprio(1);                                           \
    _Pragma("unroll")                                                        \
    for (int m = 0; m < 4; ++m)                                              \
      _Pragma("unroll")                                                      \
      for (int n = 0; n < 4; ++n)                                            \
        acc[m][n] = __builtin_amdgcn_mfma_f32_16x16x32_bf16(                 \
            af[m], bf[n], acc[m][n], 0, 0, 0);                               \
    __builtin_amdgcn_s_setprio(0);                                           \
    if (DOREAD) {                                                            \
      const u16* Ap_ = &smem[RBUF][0][wr * 128 + fr][csw];                   \
      _Pragma("unroll")                                                      \
      for (int m = 0; m < 4; ++m)                                            \
        af[m] = *(const bf16x8*)(Ap_ + m * 16 * BK);                         \
    }                                                                        \
    __builtin_amdgcn_sched_barrier(0);                                       \
    __builtin_amdgcn_s_setprio(1);                                           \
    _Pragma("unroll")                                                        \
    for (int m = 4; m < 8; ++m)                                              \
      _Pragma("unroll")                                                      \
      for (int n = 0; n < 4; ++n)                                            \
        acc[m][n] = __builtin_amdgcn_mfma_f32_16x16x32_bf16(                 \
            af[m], bf[n], acc[m][n], 0, 0, 0);                               \
    __builtin_amdgcn_s_setprio(0);                                           \
    if (DOREAD) {                                                            \
      const u16* Ap_ = &smem[RBUF][0][wr * 128 + fr][csw];                   \
      const u16* Bp_ = &smem[RBUF][1][wc * 64 + fr][csw];                    \
      _Pragma("unroll")                                                      \
      for (int m = 4; m < 8; ++m)                                            \
        af[m] = *(const bf16x8*)(Ap_ + m * 16 * BK);                         \
      _Pragma("unroll")                                                      \
      for (int n = 0; n < 4; ++n)                                            \
        bf[n] = *(const bf16x8*)(Bp_ + n * 16 * BK);                         \
    }                                                                        \
    __builtin_amdgcn_sched_barrier(0);                                       \
    WAIT;                                                                    \
    __builtin_amdgcn_s_barrier();                                            \
  } while (0)

  #define VM4 asm volatile("s_waitcnt vmcnt(4)" ::: "memory")
  #define VM0 asm volatile("s_waitcnt vmcnt(0)" ::: "memory")
  #define NOW ((void)0)

  // steady: 31 groups of 4 tiles (kt = 0..123)
  for (int ktb = 0; ktb < NKT - 4; ktb += 4) {
    K_TILE(1, 3, true, true, 0,   VM4);
    K_TILE(2, 0, true, true, 64,  VM4);
    K_TILE(3, 1, true, true, 128, VM4);
    K_TILE(0, 2, true, true, 192, VM4);
    gA0 += 256; gA1 += 256; gB0 += 256; gB1 += 256;
  }
  // peeled tail: kt = 124 (stage s127 at GOFF 0), 125, 126, 127
  K_TILE(1, 3, true,  true,  0, VM4);
  K_TILE(2, 0, false, true,  0, VM0);
  K_TILE(3, 0, false, true,  0, NOW);
  K_TILE(0, 0, false, false, 0, NOW);

  #undef K_TILE
  #undef VM4
  #undef VM0
  #undef NOW

  // ---- epilogue: bias + masked rank-8 LoRA, fp32 out ----
  const int gn0 = bn * 256 + wc * 64;
  const size_t gm0 = (size_t)bm * 256 + wr * 128;
  float wbv[4][8]; float bv[4];
  #pragma unroll
  for (int n = 0; n < 4; ++n) {
    const int gn = gn0 + n * 16 + fr;
    bv[n] = bias[gn];
    const float4 w0 = ((const float4*)(WBw + (size_t)gn * 8))[0];
    const float4 w1 = ((const float4*)(WBw + (size_t)gn * 8))[1];
    wbv[n][0] = w0.x; wbv[n][1] = w0.y; wbv[n][2] = w0.z; wbv[n][3] = w0.w;
    wbv[n][4] = w1.x; wbv[n][5] = w1.y; wbv[n][6] = w1.z; wbv[n][7] = w1.w;
  }
  #pragma unroll
  for (int m = 0; m < 8; ++m) {
    #pragma unroll
    for (int j = 0; j < 4; ++j) {
      const size_t gm = gm0 + m * 16 + fq * 4 + j;   // C/D row = (l>>4)*4+reg
      const int msk = mask[gm];
      const float4 m0 = ((const float4*)(mid + gm * 8))[0];
      const float4 m1 = ((const float4*)(mid + gm * 8))[1];
      float* orow = out + gm * (size_t)N_DIM;
      #pragma unroll
      for (int n = 0; n < 4; ++n) {
        const float lora =
            m0.x * wbv[n][0] + m0.y * wbv[n][1] + m0.z * wbv[n][2] + m0.w * wbv[n][3] +
            m1.x * wbv[n][4] + m1.y * wbv[n][5] + m1.z * wbv[n][6] + m1.w * wbv[n][7];
        orow[gn0 + n * 16 + fr] = acc[m][n][j] + bv[n] + (msk ? lora : 0.0f);
      }
    }
  }
}

extern "C" void kernel_launch(void* const* d_in, const int* in_sizes, int n_in,
                              void* d_out, int out_size, void* d_ws, size_t ws_size,
                              hipStream_t stream) {
  (void)in_sizes; (void)n_in; (void)out_size; (void)ws_size;
  const float* x     = (const float*)d_in[0];
  const int*   mask  = (const int*)d_in[1];
  const float* Wm    = (const float*)d_in[2];
  const float* bmain = (const float*)d_in[3];
  const float* WA    = (const float*)d_in[4];
  const float* WB    = (const float*)d_in[5];
  float* out = (float*)d_out;

  u16* xb  = (u16*)d_ws;                                // 64 MiB
  u16* wb  = xb + (size_t)M_TOK * K_DIM;                // 32 MiB
  float* mid = (float*)(wb + (size_t)N_DIM * K_DIM);    // 256 KiB

  k_prep<<<M_TOK + 2048, 256, 0, stream>>>(x, WA, Wm, xb, mid, wb);
  dim3 grid((M_TOK / 256) * (N_DIM / 256));             // 512 blocks
  k_gemm<<<grid, 512, 0, stream>>>(xb, wb, bmain, mask, mid, WB, out);
}